// Round 1
// baseline (12189.214 us; speedup 1.0000x reference)
//
#include <hip/hip_runtime.h>
#include <math.h>

#define N_NODES 500000
#define N_EDGES 4000000
#define FDIM 10   // IN_DIM + HID
#define HID 8

// ---------------------------------------------------------------------------
// Kernel 1: input network.  xcat[n] = [tanh(x @ win_w + win_b), x]  (10 dims)
// ---------------------------------------------------------------------------
__global__ void input_kernel(const float* __restrict__ x,      // [N,2]
                             const float* __restrict__ win_w,  // [2][8]
                             const float* __restrict__ win_b,  // [8]
                             float* __restrict__ xcat) {       // [N,10]
    int n = blockIdx.x * blockDim.x + threadIdx.x;
    if (n >= N_NODES) return;
    float x0 = x[2 * n], x1 = x[2 * n + 1];
    float* o = xcat + (size_t)n * FDIM;
#pragma unroll
    for (int j = 0; j < HID; j++) {
        float v = x0 * win_w[j] + x1 * win_w[HID + j] + win_b[j];
        o[j] = tanhf(v);
    }
    o[8] = x0;
    o[9] = x1;
}

// ---------------------------------------------------------------------------
// Kernel 2: edge network.  B = [xcat[col], xcat[row]] (20)
//   h = tanh(B @ e1_w + e1_b)  (8);  e = sigmoid(h @ e2_w + e2_b)  (1)
// SCATTER mode:  mo[row] += xcat[col]*e ;  mi[col] += xcat[row]*e
// WRITE mode:    out[i] = e
// ---------------------------------------------------------------------------
template <bool WRITE_OUT>
__global__ void edge_kernel(const int* __restrict__ row,
                            const int* __restrict__ col,
                            const float* __restrict__ xcat,   // [N,10]
                            const float* __restrict__ e1_w,   // [20][8]
                            const float* __restrict__ e1_b,   // [8]
                            const float* __restrict__ e2_w,   // [8]
                            const float* __restrict__ e2_b,   // [1]
                            float* __restrict__ mi,           // [N,10]
                            float* __restrict__ mo,           // [N,10]
                            float* __restrict__ out) {        // [E]
    __shared__ float s_e1w[20 * HID];
    __shared__ float s_e1b[HID];
    __shared__ float s_e2w[HID];
    __shared__ float s_e2b;
    int tid = threadIdx.x;
    if (tid < 160) s_e1w[tid] = e1_w[tid];
    else if (tid < 168) s_e1b[tid - 160] = e1_b[tid - 160];
    else if (tid < 176) s_e2w[tid - 168] = e2_w[tid - 168];
    else if (tid == 176) s_e2b = e2_b[0];
    __syncthreads();

    int i = blockIdx.x * blockDim.x + tid;
    if (i >= N_EDGES) return;

    int r = row[i], c = col[i];
    // 40-byte rows, 8-byte aligned -> float2 loads are safe.
    const float2* pa = (const float2*)(xcat + (size_t)c * FDIM);
    const float2* pb = (const float2*)(xcat + (size_t)r * FDIM);
    float a[FDIM], b[FDIM];
#pragma unroll
    for (int k = 0; k < 5; k++) {
        float2 va = pa[k]; a[2 * k] = va.x; a[2 * k + 1] = va.y;
        float2 vb = pb[k]; b[2 * k] = vb.x; b[2 * k + 1] = vb.y;
    }

    float dot = s_e2b;
#pragma unroll
    for (int j = 0; j < HID; j++) {
        float v = s_e1b[j];
#pragma unroll
        for (int k = 0; k < FDIM; k++) v += a[k] * s_e1w[k * HID + j];
#pragma unroll
        for (int k = 0; k < FDIM; k++) v += b[k] * s_e1w[(FDIM + k) * HID + j];
        dot += tanhf(v) * s_e2w[j];
    }
    float e = 1.0f / (1.0f + expf(-dot));

    if (WRITE_OUT) {
        out[i] = e;
    } else {
        float* po = mo + (size_t)r * FDIM;  // mo[row] += xcat[col] * e
        float* pi = mi + (size_t)c * FDIM;  // mi[col] += xcat[row] * e
#pragma unroll
        for (int k = 0; k < FDIM; k++) {
            atomicAdd(&po[k], a[k] * e);
            atomicAdd(&pi[k], b[k] * e);
        }
    }
}

// ---------------------------------------------------------------------------
// Kernel 3: node network.  M = [mi, mo, xcat] (30)
//   h = tanh(M @ n1_w + n1_b);  H = tanh(h @ n2_w + n2_b)
//   xcat[n][0:8] = H  (xcat[n][8:10] stays = x)
// ---------------------------------------------------------------------------
__global__ void node_kernel(const float* __restrict__ mi,    // [N,10]
                            const float* __restrict__ mo,    // [N,10]
                            const float* __restrict__ n1_w,  // [30][8]
                            const float* __restrict__ n1_b,  // [8]
                            const float* __restrict__ n2_w,  // [8][8]
                            const float* __restrict__ n2_b,  // [8]
                            float* __restrict__ xcat) {      // [N,10] in/out
    __shared__ float s_n1w[30 * HID];
    __shared__ float s_n1b[HID];
    __shared__ float s_n2w[HID * HID];
    __shared__ float s_n2b[HID];
    int tid = threadIdx.x;
    if (tid < 240) s_n1w[tid] = n1_w[tid];
    else if (tid < 248) s_n1b[tid - 240] = n1_b[tid - 240];
    if (tid >= 248 && tid < 312) {
        // nothing
    }
    if (tid < 64) s_n2w[tid] = n2_w[tid];
    if (tid >= 64 && tid < 72) s_n2b[tid - 64] = n2_b[tid - 64];
    __syncthreads();

    int n = blockIdx.x * blockDim.x + tid;
    if (n >= N_NODES) return;

    float M[30];
    const float2* p0 = (const float2*)(mi + (size_t)n * FDIM);
    const float2* p1 = (const float2*)(mo + (size_t)n * FDIM);
    const float2* p2 = (const float2*)(xcat + (size_t)n * FDIM);
#pragma unroll
    for (int k = 0; k < 5; k++) {
        float2 v0 = p0[k]; M[2 * k]      = v0.x; M[2 * k + 1]      = v0.y;
        float2 v1 = p1[k]; M[10 + 2 * k] = v1.x; M[10 + 2 * k + 1] = v1.y;
        float2 v2 = p2[k]; M[20 + 2 * k] = v2.x; M[20 + 2 * k + 1] = v2.y;
    }

    float h[HID];
#pragma unroll
    for (int j = 0; j < HID; j++) {
        float v = s_n1b[j];
#pragma unroll
        for (int k = 0; k < 30; k++) v += M[k] * s_n1w[k * HID + j];
        h[j] = tanhf(v);
    }
    float* o = xcat + (size_t)n * FDIM;
#pragma unroll
    for (int j = 0; j < HID; j++) {
        float v = s_n2b[j];
#pragma unroll
        for (int k = 0; k < HID; k++) v += h[k] * s_n2w[k * HID + j];
        o[j] = tanhf(v);
    }
    // o[8], o[9] remain the original x — untouched.
}

// ---------------------------------------------------------------------------
extern "C" void kernel_launch(void* const* d_in, const int* in_sizes, int n_in,
                              void* d_out, int out_size, void* d_ws, size_t ws_size,
                              hipStream_t stream) {
    const float* x      = (const float*)d_in[0];
    const int*   eidx   = (const int*)d_in[1];
    const float* win_w  = (const float*)d_in[2];
    const float* win_b  = (const float*)d_in[3];
    const float* e1_w   = (const float*)d_in[4];
    const float* e1_b   = (const float*)d_in[5];
    const float* e2_w   = (const float*)d_in[6];
    const float* e2_b   = (const float*)d_in[7];
    const float* n1_w   = (const float*)d_in[8];
    const float* n1_b   = (const float*)d_in[9];
    const float* n2_w   = (const float*)d_in[10];
    const float* n2_b   = (const float*)d_in[11];
    float* out = (float*)d_out;

    const int* row = eidx;            // edge_index[0]
    const int* col = eidx + N_EDGES;  // edge_index[1]

    float* xcat = (float*)d_ws;                      // [N,10]
    float* mi   = xcat + (size_t)N_NODES * FDIM;     // [N,10]
    float* mo   = mi + (size_t)N_NODES * FDIM;       // [N,10]

    const int BLK = 256;
    int node_blocks = (N_NODES + BLK - 1) / BLK;
    int edge_blocks = (N_EDGES + BLK - 1) / BLK;

    input_kernel<<<node_blocks, BLK, 0, stream>>>(x, win_w, win_b, xcat);

    for (int it = 0; it < 3; it++) {
        hipMemsetAsync(mi, 0, 2 * (size_t)N_NODES * FDIM * sizeof(float), stream);
        edge_kernel<false><<<edge_blocks, BLK, 0, stream>>>(
            row, col, xcat, e1_w, e1_b, e2_w, e2_b, mi, mo, nullptr);
        node_kernel<<<node_blocks, BLK, 0, stream>>>(
            mi, mo, n1_w, n1_b, n2_w, n2_b, xcat);
    }

    edge_kernel<true><<<edge_blocks, BLK, 0, stream>>>(
        row, col, xcat, e1_w, e1_b, e2_w, e2_b, nullptr, nullptr, out);
}

// Round 2
// 2814.154 us; speedup vs baseline: 4.3314x; 4.3314x over previous
//
#include <hip/hip_runtime.h>
#include <math.h>

#define N_NODES 500000
#define N_EDGES 4000000
#define FDIM 10   // IN_DIM + HID
#define HID 8

#define SCAN_BLK 256
#define SCAN_CHUNK 1024   // elements per block in the scan (4 per thread)

// ---------------------------------------------------------------------------
// Kernel 1: input network.  xcat[n] = [tanh(x @ win_w + win_b), x]  (10 dims)
// ---------------------------------------------------------------------------
__global__ void input_kernel(const float* __restrict__ x,      // [N,2]
                             const float* __restrict__ win_w,  // [2][8]
                             const float* __restrict__ win_b,  // [8]
                             float* __restrict__ xcat) {       // [N,10]
    int n = blockIdx.x * blockDim.x + threadIdx.x;
    if (n >= N_NODES) return;
    float x0 = x[2 * n], x1 = x[2 * n + 1];
    float* o = xcat + (size_t)n * FDIM;
#pragma unroll
    for (int j = 0; j < HID; j++) {
        float v = x0 * win_w[j] + x1 * win_w[HID + j] + win_b[j];
        o[j] = tanhf(v);
    }
    o[8] = x0;
    o[9] = x1;
}

// ---------------------------------------------------------------------------
// CSR build: histogram -> exclusive scan (3 kernels) -> scatter
// deg/offs layout: [0,N) = col-direction (mi), [N,2N) = row-direction (mo),
// concatenated so one scan handles both; entries is one 8M-slot array.
// ---------------------------------------------------------------------------
__global__ void hist_kernel(const int* __restrict__ row,
                            const int* __restrict__ col,
                            int* __restrict__ deg) {
    int i = blockIdx.x * blockDim.x + threadIdx.x;
    if (i >= N_EDGES) return;
    atomicAdd(&deg[col[i]], 1);
    atomicAdd(&deg[N_NODES + row[i]], 1);
}

__global__ void scan1_kernel(const int* __restrict__ deg, int* __restrict__ offs,
                             int* __restrict__ bsums, int n) {
    __shared__ int s[SCAN_BLK];
    int t = threadIdx.x;
    int base = blockIdx.x * SCAN_CHUNK + t * 4;
    int v[4]; int sum = 0;
#pragma unroll
    for (int k = 0; k < 4; k++) {
        int j = base + k;
        v[k] = (j < n) ? deg[j] : 0;
        sum += v[k];
    }
    s[t] = sum;
    __syncthreads();
    for (int off = 1; off < SCAN_BLK; off <<= 1) {
        int xv = (t >= off) ? s[t - off] : 0;
        __syncthreads();
        s[t] += xv;
        __syncthreads();
    }
    int run = s[t] - sum;  // exclusive prefix within block
#pragma unroll
    for (int k = 0; k < 4; k++) {
        int j = base + k;
        if (j < n) offs[j] = run;
        run += v[k];
    }
    if (t == SCAN_BLK - 1) bsums[blockIdx.x] = s[t];
}

__global__ void scan2_kernel(int* __restrict__ bsums, int nb) {
    __shared__ int s[1024];
    int t = threadIdx.x;
    int orig = (t < nb) ? bsums[t] : 0;
    s[t] = orig;
    __syncthreads();
    for (int off = 1; off < 1024; off <<= 1) {
        int xv = (t >= off) ? s[t - off] : 0;
        __syncthreads();
        s[t] += xv;
        __syncthreads();
    }
    if (t < nb) bsums[t] = s[t] - orig;  // exclusive
}

__global__ void scan3_kernel(int* __restrict__ offs, int* __restrict__ curs,
                             const int* __restrict__ bsums, int n) {
    int b = blockIdx.x;
    int add = bsums[b];
    int t = threadIdx.x;
#pragma unroll
    for (int k = 0; k < 4; k++) {
        int j = b * SCAN_CHUNK + t + k * SCAN_BLK;
        if (j < n) {
            int v = offs[j] + add;
            offs[j] = v;
            curs[j] = v;
        }
    }
    if (b == 0 && t == 0) offs[n] = 2 * N_EDGES;  // sentinel end
}

__global__ void scatter_kernel(const int* __restrict__ row,
                               const int* __restrict__ col,
                               int* __restrict__ curs,
                               int2* __restrict__ entries) {
    int i = blockIdx.x * blockDim.x + threadIdx.x;
    if (i >= N_EDGES) return;
    int r = row[i], c = col[i];
    int p = atomicAdd(&curs[c], 1);
    entries[p] = make_int2(r, i);  // col-CSR: other = row  -> mi
    int q = atomicAdd(&curs[N_NODES + r], 1);
    entries[q] = make_int2(c, i);  // row-CSR: other = col  -> mo
}

// ---------------------------------------------------------------------------
// Edge network: e = sigmoid(tanh([xcat[col],xcat[row]] @ e1 + b1) @ e2 + b2)
// WRITE_OUT=false -> evals[i];  true -> out[i]
// ---------------------------------------------------------------------------
template <bool WRITE_OUT>
__global__ void edge_kernel(const int* __restrict__ row,
                            const int* __restrict__ col,
                            const float* __restrict__ xcat,   // [N,10]
                            const float* __restrict__ e1_w,   // [20][8]
                            const float* __restrict__ e1_b,   // [8]
                            const float* __restrict__ e2_w,   // [8]
                            const float* __restrict__ e2_b,   // [1]
                            float* __restrict__ dst) {        // evals or out
    __shared__ float s_e1w[20 * HID];
    __shared__ float s_e1b[HID];
    __shared__ float s_e2w[HID];
    __shared__ float s_e2b;
    int tid = threadIdx.x;
    if (tid < 160) s_e1w[tid] = e1_w[tid];
    else if (tid < 168) s_e1b[tid - 160] = e1_b[tid - 160];
    else if (tid < 176) s_e2w[tid - 168] = e2_w[tid - 168];
    else if (tid == 176) s_e2b = e2_b[0];
    __syncthreads();

    int i = blockIdx.x * blockDim.x + tid;
    if (i >= N_EDGES) return;

    int r = row[i], c = col[i];
    const float2* pa = (const float2*)(xcat + (size_t)c * FDIM);
    const float2* pb = (const float2*)(xcat + (size_t)r * FDIM);
    float a[FDIM], b[FDIM];
#pragma unroll
    for (int k = 0; k < 5; k++) {
        float2 va = pa[k]; a[2 * k] = va.x; a[2 * k + 1] = va.y;
        float2 vb = pb[k]; b[2 * k] = vb.x; b[2 * k + 1] = vb.y;
    }

    float dot = s_e2b;
#pragma unroll
    for (int j = 0; j < HID; j++) {
        float v = s_e1b[j];
#pragma unroll
        for (int k = 0; k < FDIM; k++) v += a[k] * s_e1w[k * HID + j];
#pragma unroll
        for (int k = 0; k < FDIM; k++) v += b[k] * s_e1w[(FDIM + k) * HID + j];
        dot += tanhf(v) * s_e2w[j];
    }
    float e = 1.0f / (1.0f + expf(-dot));
    dst[i] = e;  // same write either mode; dst differs
    (void)WRITE_OUT;
}

// ---------------------------------------------------------------------------
// Fused gather + node network.  Per node:
//   mi = sum over col-CSR entries of xcat[other]*e
//   mo = sum over row-CSR entries of xcat[other]*e
//   h = tanh([mi,mo,xcat[n]] @ n1 + b1);  H = tanh(h @ n2 + b2)
//   xnext[n] = [H, xcat[n][8:10]]
// ---------------------------------------------------------------------------
__global__ void node_kernel(const float* __restrict__ xcat,     // [N,10] (read)
                            const int* __restrict__ offs,       // [2N+1]
                            const int2* __restrict__ entries,   // [2E]
                            const float* __restrict__ evals,    // [E]
                            const float* __restrict__ n1_w,     // [30][8]
                            const float* __restrict__ n1_b,     // [8]
                            const float* __restrict__ n2_w,     // [8][8]
                            const float* __restrict__ n2_b,     // [8]
                            float* __restrict__ xnext) {        // [N,10] (write)
    __shared__ float s_n1w[30 * HID];
    __shared__ float s_n1b[HID];
    __shared__ float s_n2w[HID * HID];
    __shared__ float s_n2b[HID];
    int tid = threadIdx.x;
    if (tid < 240) s_n1w[tid] = n1_w[tid];
    else if (tid < 248) s_n1b[tid - 240] = n1_b[tid - 240];
    if (tid < 64) s_n2w[tid] = n2_w[tid];
    else if (tid < 72) s_n2b[tid - 64] = n2_b[tid - 64];
    __syncthreads();

    int n = blockIdx.x * blockDim.x + tid;
    if (n >= N_NODES) return;

    float mi[FDIM], mo[FDIM];
#pragma unroll
    for (int k = 0; k < FDIM; k++) { mi[k] = 0.f; mo[k] = 0.f; }

    int s0 = offs[n], e0 = offs[n + 1];
    for (int p = s0; p < e0; p++) {
        int2 en = entries[p];
        float e = evals[en.y];
        const float2* px = (const float2*)(xcat + (size_t)en.x * FDIM);
#pragma unroll
        for (int k = 0; k < 5; k++) {
            float2 v = px[k];
            mi[2 * k]     += v.x * e;
            mi[2 * k + 1] += v.y * e;
        }
    }
    int s1 = offs[N_NODES + n], e1 = offs[N_NODES + n + 1];
    for (int p = s1; p < e1; p++) {
        int2 en = entries[p];
        float e = evals[en.y];
        const float2* px = (const float2*)(xcat + (size_t)en.x * FDIM);
#pragma unroll
        for (int k = 0; k < 5; k++) {
            float2 v = px[k];
            mo[2 * k]     += v.x * e;
            mo[2 * k + 1] += v.y * e;
        }
    }

    float xn[FDIM];
    const float2* pself = (const float2*)(xcat + (size_t)n * FDIM);
#pragma unroll
    for (int k = 0; k < 5; k++) {
        float2 v = pself[k];
        xn[2 * k] = v.x; xn[2 * k + 1] = v.y;
    }

    float h[HID];
#pragma unroll
    for (int j = 0; j < HID; j++) {
        float v = s_n1b[j];
#pragma unroll
        for (int k = 0; k < FDIM; k++) v += mi[k] * s_n1w[k * HID + j];
#pragma unroll
        for (int k = 0; k < FDIM; k++) v += mo[k] * s_n1w[(FDIM + k) * HID + j];
#pragma unroll
        for (int k = 0; k < FDIM; k++) v += xn[k] * s_n1w[(2 * FDIM + k) * HID + j];
        h[j] = tanhf(v);
    }
    float* o = xnext + (size_t)n * FDIM;
#pragma unroll
    for (int j = 0; j < HID; j++) {
        float v = s_n2b[j];
#pragma unroll
        for (int k = 0; k < HID; k++) v += h[k] * s_n2w[k * HID + j];
        o[j] = tanhf(v);
    }
    o[8] = xn[8];
    o[9] = xn[9];
}

// ---------------------------------------------------------------------------
extern "C" void kernel_launch(void* const* d_in, const int* in_sizes, int n_in,
                              void* d_out, int out_size, void* d_ws, size_t ws_size,
                              hipStream_t stream) {
    const float* x      = (const float*)d_in[0];
    const int*   eidx   = (const int*)d_in[1];
    const float* win_w  = (const float*)d_in[2];
    const float* win_b  = (const float*)d_in[3];
    const float* e1_w   = (const float*)d_in[4];
    const float* e1_b   = (const float*)d_in[5];
    const float* e2_w   = (const float*)d_in[6];
    const float* e2_b   = (const float*)d_in[7];
    const float* n1_w   = (const float*)d_in[8];
    const float* n1_b   = (const float*)d_in[9];
    const float* n2_w   = (const float*)d_in[10];
    const float* n2_b   = (const float*)d_in[11];
    float* out = (float*)d_out;

    const int* row = eidx;            // edge_index[0]
    const int* col = eidx + N_EDGES;  // edge_index[1]

    // Workspace layout (~128 MB):
    float* xcat0 = (float*)d_ws;                         // 5M floats
    float* xcat1 = xcat0 + (size_t)N_NODES * FDIM;       // 5M floats
    float* evals = xcat1 + (size_t)N_NODES * FDIM;       // 4M floats
    int*   deg   = (int*)evals;                          // 1M ints (reused pre-iter)
    int*   offs  = (int*)(evals + N_EDGES);              // 2N+1 ints (padded)
    int*   curs  = offs + 2 * N_NODES + 64;              // 2N ints
    int*   bsums = curs + 2 * N_NODES;                   // <=1024 ints
    int2*  entries = (int2*)(bsums + 1024);              // 2E int2 = 64 MB

    const int BLK = 256;
    int node_blocks = (N_NODES + BLK - 1) / BLK;
    int edge_blocks = (N_EDGES + BLK - 1) / BLK;
    int n2 = 2 * N_NODES;
    int scan_blocks = (n2 + SCAN_CHUNK - 1) / SCAN_CHUNK;  // 977

    // --- CSR build (once per launch) ---
    hipMemsetAsync(deg, 0, (size_t)n2 * sizeof(int), stream);
    hist_kernel<<<edge_blocks, BLK, 0, stream>>>(row, col, deg);
    scan1_kernel<<<scan_blocks, SCAN_BLK, 0, stream>>>(deg, offs, bsums, n2);
    scan2_kernel<<<1, 1024, 0, stream>>>(bsums, scan_blocks);
    scan3_kernel<<<scan_blocks, SCAN_BLK, 0, stream>>>(offs, curs, bsums, n2);
    scatter_kernel<<<edge_blocks, BLK, 0, stream>>>(row, col, curs, entries);

    // --- input network ---
    input_kernel<<<node_blocks, BLK, 0, stream>>>(x, win_w, win_b, xcat0);

    // --- message-passing iterations (ping-pong xcat) ---
    float* cur = xcat0;
    float* nxt = xcat1;
    for (int it = 0; it < 3; it++) {
        edge_kernel<false><<<edge_blocks, BLK, 0, stream>>>(
            row, col, cur, e1_w, e1_b, e2_w, e2_b, evals);
        node_kernel<<<node_blocks, BLK, 0, stream>>>(
            cur, offs, entries, evals, n1_w, n1_b, n2_w, n2_b, nxt);
        float* t = cur; cur = nxt; nxt = t;
    }

    // --- final edge network -> out ---
    edge_kernel<true><<<edge_blocks, BLK, 0, stream>>>(
        row, col, cur, e1_w, e1_b, e2_w, e2_b, out);
}

// Round 3
// 2796.597 us; speedup vs baseline: 4.3586x; 1.0063x over previous
//
#include <hip/hip_runtime.h>
#include <math.h>

#define N_NODES 500000
#define N_EDGES 4000000
#define FDIM 10   // IN_DIM + HID
#define HID 8

#define SCAN_BLK 256
#define SCAN_CHUNK 1024   // elements per block in the scan (4 per thread)

// ---------------------------------------------------------------------------
// Kernel 1: input network.  xcat[n] = [tanh(x @ win_w + win_b), x]  (10 dims)
// ---------------------------------------------------------------------------
__global__ void input_kernel(const float* __restrict__ x,      // [N,2]
                             const float* __restrict__ win_w,  // [2][8]
                             const float* __restrict__ win_b,  // [8]
                             float* __restrict__ xcat) {       // [N,10]
    int n = blockIdx.x * blockDim.x + threadIdx.x;
    if (n >= N_NODES) return;
    float x0 = x[2 * n], x1 = x[2 * n + 1];
    float* o = xcat + (size_t)n * FDIM;
#pragma unroll
    for (int j = 0; j < HID; j++) {
        float v = x0 * win_w[j] + x1 * win_w[HID + j] + win_b[j];
        o[j] = tanhf(v);
    }
    o[8] = x0;
    o[9] = x1;
}

// ---------------------------------------------------------------------------
// CSR build: histogram -> exclusive scan (3 kernels) -> scatter
// deg/offs layout: [0,N) = col-direction (mi), [N,2N) = row-direction (mo).
// entries[p] = other-endpoint node id (4 bytes only).
// ---------------------------------------------------------------------------
__global__ void hist_kernel(const int* __restrict__ row,
                            const int* __restrict__ col,
                            int* __restrict__ deg) {
    int i = blockIdx.x * blockDim.x + threadIdx.x;
    if (i >= N_EDGES) return;
    atomicAdd(&deg[col[i]], 1);
    atomicAdd(&deg[N_NODES + row[i]], 1);
}

__global__ void scan1_kernel(const int* __restrict__ deg, int* __restrict__ offs,
                             int* __restrict__ bsums, int n) {
    __shared__ int s[SCAN_BLK];
    int t = threadIdx.x;
    int base = blockIdx.x * SCAN_CHUNK + t * 4;
    int v[4]; int sum = 0;
#pragma unroll
    for (int k = 0; k < 4; k++) {
        int j = base + k;
        v[k] = (j < n) ? deg[j] : 0;
        sum += v[k];
    }
    s[t] = sum;
    __syncthreads();
    for (int off = 1; off < SCAN_BLK; off <<= 1) {
        int xv = (t >= off) ? s[t - off] : 0;
        __syncthreads();
        s[t] += xv;
        __syncthreads();
    }
    int run = s[t] - sum;  // exclusive prefix within block
#pragma unroll
    for (int k = 0; k < 4; k++) {
        int j = base + k;
        if (j < n) offs[j] = run;
        run += v[k];
    }
    if (t == SCAN_BLK - 1) bsums[blockIdx.x] = s[t];
}

__global__ void scan2_kernel(int* __restrict__ bsums, int nb) {
    __shared__ int s[1024];
    int t = threadIdx.x;
    int orig = (t < nb) ? bsums[t] : 0;
    s[t] = orig;
    __syncthreads();
    for (int off = 1; off < 1024; off <<= 1) {
        int xv = (t >= off) ? s[t - off] : 0;
        __syncthreads();
        s[t] += xv;
        __syncthreads();
    }
    if (t < nb) bsums[t] = s[t] - orig;  // exclusive
}

__global__ void scan3_kernel(int* __restrict__ offs, int* __restrict__ curs,
                             const int* __restrict__ bsums, int n) {
    int b = blockIdx.x;
    int add = bsums[b];
    int t = threadIdx.x;
#pragma unroll
    for (int k = 0; k < 4; k++) {
        int j = b * SCAN_CHUNK + t + k * SCAN_BLK;
        if (j < n) {
            int v = offs[j] + add;
            offs[j] = v;
            curs[j] = v;
        }
    }
    if (b == 0 && t == 0) offs[n] = 2 * N_EDGES;  // sentinel end
}

__global__ void scatter_kernel(const int* __restrict__ row,
                               const int* __restrict__ col,
                               int* __restrict__ curs,
                               int* __restrict__ entries) {
    int i = blockIdx.x * blockDim.x + threadIdx.x;
    if (i >= N_EDGES) return;
    int r = row[i], c = col[i];
    int p = atomicAdd(&curs[c], 1);
    entries[p] = r;                    // col-CSR: other = row  -> mi
    int q = atomicAdd(&curs[N_NODES + r], 1);
    entries[q] = c;                    // row-CSR: other = col  -> mo
}

// ---------------------------------------------------------------------------
// Final edge network -> out.  e = sigmoid(tanh([x[col],x[row]]@e1+b1)@e2+b2)
// ---------------------------------------------------------------------------
__global__ void edge_kernel(const int* __restrict__ row,
                            const int* __restrict__ col,
                            const float* __restrict__ xcat,   // [N,10]
                            const float* __restrict__ e1_w,   // [20][8]
                            const float* __restrict__ e1_b,   // [8]
                            const float* __restrict__ e2_w,   // [8]
                            const float* __restrict__ e2_b,   // [1]
                            float* __restrict__ out) {        // [E]
    __shared__ float s_e1w[20 * HID];
    __shared__ float s_e1b[HID];
    __shared__ float s_e2w[HID];
    __shared__ float s_e2b;
    int tid = threadIdx.x;
    if (tid < 160) s_e1w[tid] = e1_w[tid];
    else if (tid < 168) s_e1b[tid - 160] = e1_b[tid - 160];
    else if (tid < 176) s_e2w[tid - 168] = e2_w[tid - 168];
    else if (tid == 176) s_e2b = e2_b[0];
    __syncthreads();

    int i = blockIdx.x * blockDim.x + tid;
    if (i >= N_EDGES) return;

    int r = row[i], c = col[i];
    const float2* pa = (const float2*)(xcat + (size_t)c * FDIM);
    const float2* pb = (const float2*)(xcat + (size_t)r * FDIM);
    float a[FDIM], b[FDIM];
#pragma unroll
    for (int k = 0; k < 5; k++) {
        float2 va = pa[k]; a[2 * k] = va.x; a[2 * k + 1] = va.y;
        float2 vb = pb[k]; b[2 * k] = vb.x; b[2 * k + 1] = vb.y;
    }

    float dot = s_e2b;
#pragma unroll
    for (int j = 0; j < HID; j++) {
        float v = s_e1b[j];
#pragma unroll
        for (int k = 0; k < FDIM; k++) v += a[k] * s_e1w[k * HID + j];
#pragma unroll
        for (int k = 0; k < FDIM; k++) v += b[k] * s_e1w[(FDIM + k) * HID + j];
        dot += tanhf(v) * s_e2w[j];
    }
    out[i] = 1.0f / (1.0f + expf(-dot));
}

// ---------------------------------------------------------------------------
// Fused edge+gather+node network.  Per node n:
//   u_self = xcat[n] @ e1_w[0:10]    (col-side partial)
//   v_self = xcat[n] @ e1_w[10:20]   (row-side partial)
//   mi: for each col-CSR entry (other=row):
//       e = sig(tanh(u_self + (xcat[o] @ e1_bot) + b1) @ e2 + b2); mi += xcat[o]*e
//   mo: for each row-CSR entry (other=col):
//       e = sig(tanh((xcat[o] @ e1_top) + v_self + b1) @ e2 + b2); mo += xcat[o]*e
//   h = tanh([mi,mo,xcat[n]] @ n1 + b1);  H = tanh(h @ n2 + b2)
//   xnext[n] = [H, xcat[n][8:10]]
// ---------------------------------------------------------------------------
__global__ void node_kernel(const float* __restrict__ xcat,     // [N,10] (read)
                            const int* __restrict__ offs,       // [2N+1]
                            const int* __restrict__ entries,    // [2E]
                            const float* __restrict__ e1_w,     // [20][8]
                            const float* __restrict__ e1_b,     // [8]
                            const float* __restrict__ e2_w,     // [8]
                            const float* __restrict__ e2_b,     // [1]
                            const float* __restrict__ n1_w,     // [30][8]
                            const float* __restrict__ n1_b,     // [8]
                            const float* __restrict__ n2_w,     // [8][8]
                            const float* __restrict__ n2_b,     // [8]
                            float* __restrict__ xnext) {        // [N,10] (write)
    __shared__ float s_e1w[20 * HID];
    __shared__ float s_e1b[HID];
    __shared__ float s_e2w[HID];
    __shared__ float s_e2b;
    __shared__ float s_n1w[30 * HID];
    __shared__ float s_n1b[HID];
    __shared__ float s_n2w[HID * HID];
    __shared__ float s_n2b[HID];
    int tid = threadIdx.x;
    if (tid < 160) s_e1w[tid] = e1_w[tid];
    else if (tid < 168) s_e1b[tid - 160] = e1_b[tid - 160];
    else if (tid < 176) s_e2w[tid - 168] = e2_w[tid - 168];
    else if (tid == 176) s_e2b = e2_b[0];
    if (tid < 240) s_n1w[tid] = n1_w[tid];
    else if (tid < 248) s_n1b[tid - 240] = n1_b[tid - 240];
    if (tid < 64) s_n2w[tid] = n2_w[tid];
    else if (tid < 72) s_n2b[tid - 64] = n2_b[tid - 64];
    __syncthreads();

    int n = blockIdx.x * blockDim.x + tid;
    if (n >= N_NODES) return;

    // own features + partials
    float xn[FDIM];
    const float2* pself = (const float2*)(xcat + (size_t)n * FDIM);
#pragma unroll
    for (int k = 0; k < 5; k++) {
        float2 v = pself[k];
        xn[2 * k] = v.x; xn[2 * k + 1] = v.y;
    }
    float u_self[HID], v_self[HID];
#pragma unroll
    for (int j = 0; j < HID; j++) {
        float u = 0.f, v = 0.f;
#pragma unroll
        for (int k = 0; k < FDIM; k++) {
            u += xn[k] * s_e1w[k * HID + j];
            v += xn[k] * s_e1w[(FDIM + k) * HID + j];
        }
        u_self[j] = u; v_self[j] = v;
    }

    float mi[FDIM], mo[FDIM];
#pragma unroll
    for (int k = 0; k < FDIM; k++) { mi[k] = 0.f; mo[k] = 0.f; }

    // --- mi: n is col; other = row ---
    int s0 = offs[n], e0 = offs[n + 1];
    for (int p = s0; p < e0; p++) {
        int o = entries[p];
        const float2* px = (const float2*)(xcat + (size_t)o * FDIM);
        float xo[FDIM];
#pragma unroll
        for (int k = 0; k < 5; k++) {
            float2 v = px[k]; xo[2 * k] = v.x; xo[2 * k + 1] = v.y;
        }
        float d = s_e2b;
#pragma unroll
        for (int j = 0; j < HID; j++) {
            float v = u_self[j] + s_e1b[j];
#pragma unroll
            for (int k = 0; k < FDIM; k++) v += xo[k] * s_e1w[(FDIM + k) * HID + j];
            d += tanhf(v) * s_e2w[j];
        }
        float e = 1.0f / (1.0f + expf(-d));
#pragma unroll
        for (int k = 0; k < FDIM; k++) mi[k] += xo[k] * e;
    }

    // --- mo: n is row; other = col ---
    int s1 = offs[N_NODES + n], e1 = offs[N_NODES + n + 1];
    for (int p = s1; p < e1; p++) {
        int o = entries[p];
        const float2* px = (const float2*)(xcat + (size_t)o * FDIM);
        float xo[FDIM];
#pragma unroll
        for (int k = 0; k < 5; k++) {
            float2 v = px[k]; xo[2 * k] = v.x; xo[2 * k + 1] = v.y;
        }
        float d = s_e2b;
#pragma unroll
        for (int j = 0; j < HID; j++) {
            float v = v_self[j] + s_e1b[j];
#pragma unroll
            for (int k = 0; k < FDIM; k++) v += xo[k] * s_e1w[k * HID + j];
            d += tanhf(v) * s_e2w[j];
        }
        float e = 1.0f / (1.0f + expf(-d));
#pragma unroll
        for (int k = 0; k < FDIM; k++) mo[k] += xo[k] * e;
    }

    // --- node MLP ---
    float h[HID];
#pragma unroll
    for (int j = 0; j < HID; j++) {
        float v = s_n1b[j];
#pragma unroll
        for (int k = 0; k < FDIM; k++) v += mi[k] * s_n1w[k * HID + j];
#pragma unroll
        for (int k = 0; k < FDIM; k++) v += mo[k] * s_n1w[(FDIM + k) * HID + j];
#pragma unroll
        for (int k = 0; k < FDIM; k++) v += xn[k] * s_n1w[(2 * FDIM + k) * HID + j];
        h[j] = tanhf(v);
    }
    float* o = xnext + (size_t)n * FDIM;
#pragma unroll
    for (int j = 0; j < HID; j++) {
        float v = s_n2b[j];
#pragma unroll
        for (int k = 0; k < HID; k++) v += h[k] * s_n2w[k * HID + j];
        o[j] = tanhf(v);
    }
    o[8] = xn[8];
    o[9] = xn[9];
}

// ---------------------------------------------------------------------------
extern "C" void kernel_launch(void* const* d_in, const int* in_sizes, int n_in,
                              void* d_out, int out_size, void* d_ws, size_t ws_size,
                              hipStream_t stream) {
    const float* x      = (const float*)d_in[0];
    const int*   eidx   = (const int*)d_in[1];
    const float* win_w  = (const float*)d_in[2];
    const float* win_b  = (const float*)d_in[3];
    const float* e1_w   = (const float*)d_in[4];
    const float* e1_b   = (const float*)d_in[5];
    const float* e2_w   = (const float*)d_in[6];
    const float* e2_b   = (const float*)d_in[7];
    const float* n1_w   = (const float*)d_in[8];
    const float* n1_b   = (const float*)d_in[9];
    const float* n2_w   = (const float*)d_in[10];
    const float* n2_b   = (const float*)d_in[11];
    float* out = (float*)d_out;

    const int* row = eidx;            // edge_index[0]
    const int* col = eidx + N_EDGES;  // edge_index[1]

    // Workspace layout (~84 MB):
    float* xcat0 = (float*)d_ws;                         // 5M floats
    float* xcat1 = xcat0 + (size_t)N_NODES * FDIM;       // 5M floats
    int*   deg   = (int*)(xcat1 + (size_t)N_NODES * FDIM); // 2N ints... (1M)
    int*   offs  = deg + 2 * N_NODES;                    // 2N+1 ints (+pad)
    int*   curs  = offs + 2 * N_NODES + 64;              // 2N ints
    int*   bsums = curs + 2 * N_NODES;                   // <=1024 ints
    int*   entries = bsums + 1024;                       // 2E ints = 32 MB

    const int BLK = 256;
    int node_blocks = (N_NODES + BLK - 1) / BLK;
    int edge_blocks = (N_EDGES + BLK - 1) / BLK;
    int n2 = 2 * N_NODES;
    int scan_blocks = (n2 + SCAN_CHUNK - 1) / SCAN_CHUNK;  // 977

    // --- CSR build (once per launch) ---
    hipMemsetAsync(deg, 0, (size_t)n2 * sizeof(int), stream);
    hist_kernel<<<edge_blocks, BLK, 0, stream>>>(row, col, deg);
    scan1_kernel<<<scan_blocks, SCAN_BLK, 0, stream>>>(deg, offs, bsums, n2);
    scan2_kernel<<<1, 1024, 0, stream>>>(bsums, scan_blocks);
    scan3_kernel<<<scan_blocks, SCAN_BLK, 0, stream>>>(offs, curs, bsums, n2);
    scatter_kernel<<<edge_blocks, BLK, 0, stream>>>(row, col, curs, entries);

    // --- input network ---
    input_kernel<<<node_blocks, BLK, 0, stream>>>(x, win_w, win_b, xcat0);

    // --- message-passing iterations (ping-pong xcat); edge net fused in ---
    float* cur = xcat0;
    float* nxt = xcat1;
    for (int it = 0; it < 3; it++) {
        node_kernel<<<node_blocks, BLK, 0, stream>>>(
            cur, offs, entries, e1_w, e1_b, e2_w, e2_b,
            n1_w, n1_b, n2_w, n2_b, nxt);
        float* t = cur; cur = nxt; nxt = t;
    }

    // --- final edge network -> out ---
    edge_kernel<<<edge_blocks, BLK, 0, stream>>>(
        row, col, cur, e1_w, e1_b, e2_w, e2_b, out);
}

// Round 4
// 1516.243 us; speedup vs baseline: 8.0391x; 1.8444x over previous
//
#include <hip/hip_runtime.h>
#include <math.h>

#define N_NODES 500000
#define N_EDGES 4000000
#define FDIM 10   // IN_DIM + HID
#define HID 8

// Dest space: interleaved, dest = 2*col (mi side) or 2*row+1 (mo side).
// D = 2*N_NODES = 1,000,000.  512 buckets of 2048 dests (1024 nodes).
#define DSPACE (2 * N_NODES)
#define NB 512
#define BSHIFT 11            // dest >> 11 = bucket
#define BMASK 2047
#define NB_USED ((DSPACE + BMASK) / 2048)   // 489

// ---------------------------------------------------------------------------
// Fast transcendentals via hw v_exp_f32 / v_rcp_f32 (error ~1e-6, threshold 1.35e-2)
// ---------------------------------------------------------------------------
__device__ __forceinline__ float fast_tanh(float x) {
    float e = __builtin_amdgcn_exp2f(x * 2.885390082f);  // exp(2x)
    return 1.0f - 2.0f * __builtin_amdgcn_rcpf(e + 1.0f);
}
__device__ __forceinline__ float fast_sigmoid(float x) {
    float e = __builtin_amdgcn_exp2f(-1.442695041f * x); // exp(-x)
    return __builtin_amdgcn_rcpf(1.0f + e);
}

// ---------------------------------------------------------------------------
// Input network: xcat[n] = [tanh(x @ win_w + win_b), x]
// ---------------------------------------------------------------------------
__global__ void input_kernel(const float* __restrict__ x,
                             const float* __restrict__ win_w,
                             const float* __restrict__ win_b,
                             float* __restrict__ xcat) {
    int n = blockIdx.x * blockDim.x + threadIdx.x;
    if (n >= N_NODES) return;
    float x0 = x[2 * n], x1 = x[2 * n + 1];
    float* o = xcat + (size_t)n * FDIM;
#pragma unroll
    for (int j = 0; j < HID; j++) {
        float v = x0 * win_w[j] + x1 * win_w[HID + j] + win_b[j];
        o[j] = fast_tanh(v);
    }
    o[8] = x0;
    o[9] = x1;
}

// ---------------------------------------------------------------------------
// K0: bucket histogram, LDS-staged.  256 thr x 16 edges = 4096 edges/block.
// ---------------------------------------------------------------------------
__global__ void bucket_hist_kernel(const int* __restrict__ row,
                                   const int* __restrict__ col,
                                   int* __restrict__ g_cnt) {  // [NB]
    __shared__ int s_cnt[NB];
    int tid = threadIdx.x;
    for (int i = tid; i < NB; i += 256) s_cnt[i] = 0;
    __syncthreads();
    int base = blockIdx.x * 4096;
#pragma unroll
    for (int k = 0; k < 16; k++) {
        int e = base + k * 256 + tid;
        if (e < N_EDGES) {
            int c = col[e], r = row[e];
            atomicAdd(&s_cnt[(2 * c) >> BSHIFT], 1);
            atomicAdd(&s_cnt[(2 * r + 1) >> BSHIFT], 1);
        }
    }
    __syncthreads();
    for (int i = tid; i < NB; i += 256) {
        int v = s_cnt[i];
        if (v) atomicAdd(&g_cnt[i], v);
    }
}

// ---------------------------------------------------------------------------
// K1: exclusive scan of the 512 bucket counts (one block of 512 threads).
// ---------------------------------------------------------------------------
__global__ void bucket_scan_kernel(const int* __restrict__ g_cnt,
                                   int* __restrict__ bucket_base,  // [NB+1]
                                   int* __restrict__ bucket_cur) { // [NB]
    __shared__ int s[NB];
    int t = threadIdx.x;
    int c = g_cnt[t];
    s[t] = c;
    __syncthreads();
    for (int off = 1; off < NB; off <<= 1) {
        int v = (t >= off) ? s[t - off] : 0;
        __syncthreads();
        s[t] += v;
        __syncthreads();
    }
    int ex = s[t] - c;  // exclusive
    bucket_base[t] = ex;
    bucket_cur[t] = ex;
    if (t == NB - 1) bucket_base[NB] = s[t];
}

// ---------------------------------------------------------------------------
// K2: binning.  1024 thr x 4 edges = 4096 edges (8192 items) per block.
// Items staged in LDS by bucket, flushed with one global atomic per
// (block,bucket) chunk reservation -> coalesced sequential appends.
// Packed item = (dest_local[11] << 19) | other[19].
// ---------------------------------------------------------------------------
__global__ void bin_kernel(const int* __restrict__ row,
                           const int* __restrict__ col,
                           int* __restrict__ bucket_cur,          // [NB]
                           unsigned int* __restrict__ binned) {   // [2E]
    __shared__ int s_cnt[NB];
    __shared__ int s_start[NB];
    __shared__ int s_cur[NB];
    __shared__ int s_gbase[NB];
    __shared__ unsigned int s_items[8192];
    __shared__ unsigned short s_ibkt[8192];

    int tid = threadIdx.x;
    if (tid < NB) s_cnt[tid] = 0;
    __syncthreads();

    int base = blockIdx.x * 4096;
    int cc[4], rr[4];
#pragma unroll
    for (int k = 0; k < 4; k++) {
        int e = base + k * 1024 + tid;
        bool ok = (e < N_EDGES);
        cc[k] = ok ? col[e] : -1;
        rr[k] = ok ? row[e] : -1;
        if (ok) {
            atomicAdd(&s_cnt[(2 * cc[k]) >> BSHIFT], 1);
            atomicAdd(&s_cnt[(2 * rr[k] + 1) >> BSHIFT], 1);
        }
    }
    __syncthreads();

    // exclusive scan of s_cnt into s_start (Hillis-Steele, tid<512 active)
    if (tid < NB) s_start[tid] = s_cnt[tid];
    __syncthreads();
    for (int off = 1; off < NB; off <<= 1) {
        int v = 0;
        if (tid < NB && tid >= off) v = s_start[tid - off];
        __syncthreads();
        if (tid < NB) s_start[tid] += v;
        __syncthreads();
    }
    if (tid < NB) {
        int ex = s_start[tid] - s_cnt[tid];
        s_start[tid] = ex;
        s_cur[tid] = ex;
    }
    __syncthreads();

    // scatter items into LDS staging
#pragma unroll
    for (int k = 0; k < 4; k++) {
        if (cc[k] >= 0) {
            int d0 = 2 * cc[k];
            int b0 = d0 >> BSHIFT;
            int s0 = atomicAdd(&s_cur[b0], 1);
            s_items[s0] = ((unsigned)(d0 & BMASK) << 19) | (unsigned)rr[k];
            s_ibkt[s0] = (unsigned short)b0;
            int d1 = 2 * rr[k] + 1;
            int b1 = d1 >> BSHIFT;
            int s1 = atomicAdd(&s_cur[b1], 1);
            s_items[s1] = ((unsigned)(d1 & BMASK) << 19) | (unsigned)cc[k];
            s_ibkt[s1] = (unsigned short)b1;
        }
    }
    __syncthreads();

    // reserve global chunks (one atomic per bucket per block)
    if (tid < NB) s_gbase[tid] = atomicAdd(&bucket_cur[tid], s_cnt[tid]);
    __syncthreads();

    // flush: consecutive staged slots of a bucket -> consecutive global slots
    int tot = s_start[NB - 1] + s_cnt[NB - 1];
    for (int s = tid; s < tot; s += 1024) {
        int b = s_ibkt[s];
        int g = s_gbase[b] + (s - s_start[b]);
        binned[g] = s_items[s];
    }
}

// ---------------------------------------------------------------------------
// K3: CSR finalize, one block (1024 thr) per bucket.  Degrees, scan, and
// cursors entirely in LDS; entries written into the bucket's contiguous
// (L2-resident) window.  No global atomics.
// ---------------------------------------------------------------------------
__global__ void csr_kernel(const unsigned int* __restrict__ binned,  // [2E]
                           const int* __restrict__ bucket_base,      // [NB+1]
                           int* __restrict__ offs,                   // [D+1]
                           int* __restrict__ entries) {              // [2E]
    __shared__ int s_deg[2048];
    __shared__ int s_off[2048];
    __shared__ int s_cur[2048];
    __shared__ int s_pair[1024];

    int t = threadIdx.x;
    int b = blockIdx.x;
    if (b == 0 && t == 0) offs[DSPACE] = 2 * N_EDGES;  // sentinel

    int ebase = bucket_base[b];
    int eend = bucket_base[b + 1];

    s_deg[t] = 0;
    s_deg[t + 1024] = 0;
    __syncthreads();

    for (int p = ebase + t; p < eend; p += 1024)
        atomicAdd(&s_deg[binned[p] >> 19], 1);
    __syncthreads();

    // exclusive scan over 2048 via pair-sum + 1024-wide Hillis-Steele
    int d0 = s_deg[2 * t], d1 = s_deg[2 * t + 1];
    s_pair[t] = d0 + d1;
    __syncthreads();
    for (int off = 1; off < 1024; off <<= 1) {
        int v = (t >= off) ? s_pair[t - off] : 0;
        __syncthreads();
        s_pair[t] += v;
        __syncthreads();
    }
    int pex = s_pair[t] - (d0 + d1);
    s_off[2 * t] = pex;
    s_off[2 * t + 1] = pex + d0;
    s_cur[2 * t] = pex;
    s_cur[2 * t + 1] = pex + d0;

    // write global offs (coalesced-ish)
    int dest0 = b * 2048 + 2 * t;
    if (dest0 < DSPACE) offs[dest0] = ebase + pex;
    if (dest0 + 1 < DSPACE) offs[dest0 + 1] = ebase + pex + d0;
    __syncthreads();

    // scatter entries within the bucket window
    for (int p = ebase + t; p < eend; p += 1024) {
        unsigned int it = binned[p];
        int dl = it >> 19;
        int other = it & 0x7FFFF;
        int pos = atomicAdd(&s_cur[dl], 1);
        entries[ebase + pos] = other;
    }
}

// ---------------------------------------------------------------------------
// Final edge network -> out
// ---------------------------------------------------------------------------
__global__ void edge_kernel(const int* __restrict__ row,
                            const int* __restrict__ col,
                            const float* __restrict__ xcat,
                            const float* __restrict__ e1_w,
                            const float* __restrict__ e1_b,
                            const float* __restrict__ e2_w,
                            const float* __restrict__ e2_b,
                            float* __restrict__ out) {
    __shared__ float s_e1w[20 * HID];
    __shared__ float s_e1b[HID];
    __shared__ float s_e2w[HID];
    __shared__ float s_e2b;
    int tid = threadIdx.x;
    if (tid < 160) s_e1w[tid] = e1_w[tid];
    else if (tid < 168) s_e1b[tid - 160] = e1_b[tid - 160];
    else if (tid < 176) s_e2w[tid - 168] = e2_w[tid - 168];
    else if (tid == 176) s_e2b = e2_b[0];
    __syncthreads();

    int i = blockIdx.x * blockDim.x + tid;
    if (i >= N_EDGES) return;

    int r = row[i], c = col[i];
    const float2* pa = (const float2*)(xcat + (size_t)c * FDIM);
    const float2* pb = (const float2*)(xcat + (size_t)r * FDIM);
    float a[FDIM], bb[FDIM];
#pragma unroll
    for (int k = 0; k < 5; k++) {
        float2 va = pa[k]; a[2 * k] = va.x; a[2 * k + 1] = va.y;
        float2 vb = pb[k]; bb[2 * k] = vb.x; bb[2 * k + 1] = vb.y;
    }

    float dot = s_e2b;
#pragma unroll
    for (int j = 0; j < HID; j++) {
        float v = s_e1b[j];
#pragma unroll
        for (int k = 0; k < FDIM; k++) v += a[k] * s_e1w[k * HID + j];
#pragma unroll
        for (int k = 0; k < FDIM; k++) v += bb[k] * s_e1w[(FDIM + k) * HID + j];
        dot += fast_tanh(v) * s_e2w[j];
    }
    out[i] = fast_sigmoid(dot);
}

// ---------------------------------------------------------------------------
// Fused edge+gather+node network (offsets now interleaved: offs[2n..2n+2]).
// ---------------------------------------------------------------------------
__global__ void node_kernel(const float* __restrict__ xcat,
                            const int* __restrict__ offs,      // [D+1]
                            const int* __restrict__ entries,   // [2E]
                            const float* __restrict__ e1_w,
                            const float* __restrict__ e1_b,
                            const float* __restrict__ e2_w,
                            const float* __restrict__ e2_b,
                            const float* __restrict__ n1_w,
                            const float* __restrict__ n1_b,
                            const float* __restrict__ n2_w,
                            const float* __restrict__ n2_b,
                            float* __restrict__ xnext) {
    __shared__ float s_e1w[20 * HID];
    __shared__ float s_e1b[HID];
    __shared__ float s_e2w[HID];
    __shared__ float s_e2b;
    __shared__ float s_n1w[30 * HID];
    __shared__ float s_n1b[HID];
    __shared__ float s_n2w[HID * HID];
    __shared__ float s_n2b[HID];
    int tid = threadIdx.x;
    if (tid < 160) s_e1w[tid] = e1_w[tid];
    else if (tid < 168) s_e1b[tid - 160] = e1_b[tid - 160];
    else if (tid < 176) s_e2w[tid - 168] = e2_w[tid - 168];
    else if (tid == 176) s_e2b = e2_b[0];
    if (tid < 240) s_n1w[tid] = n1_w[tid];
    else if (tid < 248) s_n1b[tid - 240] = n1_b[tid - 240];
    if (tid < 64) s_n2w[tid] = n2_w[tid];
    else if (tid < 72) s_n2b[tid - 64] = n2_b[tid - 64];
    __syncthreads();

    int n = blockIdx.x * blockDim.x + tid;
    if (n >= N_NODES) return;

    float xn[FDIM];
    const float2* pself = (const float2*)(xcat + (size_t)n * FDIM);
#pragma unroll
    for (int k = 0; k < 5; k++) {
        float2 v = pself[k];
        xn[2 * k] = v.x; xn[2 * k + 1] = v.y;
    }
    float u_self[HID], v_self[HID];
#pragma unroll
    for (int j = 0; j < HID; j++) {
        float u = 0.f, v = 0.f;
#pragma unroll
        for (int k = 0; k < FDIM; k++) {
            u += xn[k] * s_e1w[k * HID + j];
            v += xn[k] * s_e1w[(FDIM + k) * HID + j];
        }
        u_self[j] = u; v_self[j] = v;
    }

    float mi[FDIM], mo[FDIM];
#pragma unroll
    for (int k = 0; k < FDIM; k++) { mi[k] = 0.f; mo[k] = 0.f; }

    int base2 = 2 * n;
    int s0 = offs[base2], e0 = offs[base2 + 1], e1 = offs[base2 + 2];

    // mi: n is col; other = row
    for (int p = s0; p < e0; p++) {
        int o = entries[p];
        const float2* px = (const float2*)(xcat + (size_t)o * FDIM);
        float xo[FDIM];
#pragma unroll
        for (int k = 0; k < 5; k++) {
            float2 v = px[k]; xo[2 * k] = v.x; xo[2 * k + 1] = v.y;
        }
        float d = s_e2b;
#pragma unroll
        for (int j = 0; j < HID; j++) {
            float v = u_self[j] + s_e1b[j];
#pragma unroll
            for (int k = 0; k < FDIM; k++) v += xo[k] * s_e1w[(FDIM + k) * HID + j];
            d += fast_tanh(v) * s_e2w[j];
        }
        float e = fast_sigmoid(d);
#pragma unroll
        for (int k = 0; k < FDIM; k++) mi[k] += xo[k] * e;
    }

    // mo: n is row; other = col
    for (int p = e0; p < e1; p++) {
        int o = entries[p];
        const float2* px = (const float2*)(xcat + (size_t)o * FDIM);
        float xo[FDIM];
#pragma unroll
        for (int k = 0; k < 5; k++) {
            float2 v = px[k]; xo[2 * k] = v.x; xo[2 * k + 1] = v.y;
        }
        float d = s_e2b;
#pragma unroll
        for (int j = 0; j < HID; j++) {
            float v = v_self[j] + s_e1b[j];
#pragma unroll
            for (int k = 0; k < FDIM; k++) v += xo[k] * s_e1w[k * HID + j];
            d += fast_tanh(v) * s_e2w[j];
        }
        float e = fast_sigmoid(d);
#pragma unroll
        for (int k = 0; k < FDIM; k++) mo[k] += xo[k] * e;
    }

    float h[HID];
#pragma unroll
    for (int j = 0; j < HID; j++) {
        float v = s_n1b[j];
#pragma unroll
        for (int k = 0; k < FDIM; k++) v += mi[k] * s_n1w[k * HID + j];
#pragma unroll
        for (int k = 0; k < FDIM; k++) v += mo[k] * s_n1w[(FDIM + k) * HID + j];
#pragma unroll
        for (int k = 0; k < FDIM; k++) v += xn[k] * s_n1w[(2 * FDIM + k) * HID + j];
        h[j] = fast_tanh(v);
    }
    float* o = xnext + (size_t)n * FDIM;
#pragma unroll
    for (int j = 0; j < HID; j++) {
        float v = s_n2b[j];
#pragma unroll
        for (int k = 0; k < HID; k++) v += h[k] * s_n2w[k * HID + j];
        o[j] = fast_tanh(v);
    }
    o[8] = xn[8];
    o[9] = xn[9];
}

// ---------------------------------------------------------------------------
extern "C" void kernel_launch(void* const* d_in, const int* in_sizes, int n_in,
                              void* d_out, int out_size, void* d_ws, size_t ws_size,
                              hipStream_t stream) {
    const float* x      = (const float*)d_in[0];
    const int*   eidx   = (const int*)d_in[1];
    const float* win_w  = (const float*)d_in[2];
    const float* win_b  = (const float*)d_in[3];
    const float* e1_w   = (const float*)d_in[4];
    const float* e1_b   = (const float*)d_in[5];
    const float* e2_w   = (const float*)d_in[6];
    const float* e2_b   = (const float*)d_in[7];
    const float* n1_w   = (const float*)d_in[8];
    const float* n1_b   = (const float*)d_in[9];
    const float* n2_w   = (const float*)d_in[10];
    const float* n2_b   = (const float*)d_in[11];
    float* out = (float*)d_out;

    const int* row = eidx;            // edge_index[0]
    const int* col = eidx + N_EDGES;  // edge_index[1]

    // Workspace layout (~108 MB):
    float* xcat0 = (float*)d_ws;                           // 5M floats
    float* xcat1 = xcat0 + (size_t)N_NODES * FDIM;         // 5M floats
    int* offs        = (int*)(xcat1 + (size_t)N_NODES * FDIM); // D+1 (pad 1,000,064)
    int* g_cnt       = offs + DSPACE + 64;                 // 512
    int* bucket_base = g_cnt + NB;                         // 513 (pad 576)
    int* bucket_cur  = bucket_base + NB + 64;              // 512
    unsigned int* binned = (unsigned int*)(bucket_cur + NB);   // 2E = 32 MB
    int* entries = (int*)(binned + 2 * (size_t)N_EDGES);   // 2E = 32 MB

    const int BLK = 256;
    int node_blocks = (N_NODES + BLK - 1) / BLK;
    int edge_blocks = (N_EDGES + BLK - 1) / BLK;
    int chunk_blocks = (N_EDGES + 4095) / 4096;  // 977

    // --- CSR build: zero global atomics per item ---
    hipMemsetAsync(g_cnt, 0, NB * sizeof(int), stream);
    bucket_hist_kernel<<<chunk_blocks, 256, 0, stream>>>(row, col, g_cnt);
    bucket_scan_kernel<<<1, NB, 0, stream>>>(g_cnt, bucket_base, bucket_cur);
    bin_kernel<<<chunk_blocks, 1024, 0, stream>>>(row, col, bucket_cur, binned);
    csr_kernel<<<NB_USED, 1024, 0, stream>>>(binned, bucket_base, offs, entries);

    // --- input network ---
    input_kernel<<<node_blocks, BLK, 0, stream>>>(x, win_w, win_b, xcat0);

    // --- message-passing iterations (ping-pong xcat) ---
    float* cur = xcat0;
    float* nxt = xcat1;
    for (int it = 0; it < 3; it++) {
        node_kernel<<<node_blocks, BLK, 0, stream>>>(
            cur, offs, entries, e1_w, e1_b, e2_w, e2_b,
            n1_w, n1_b, n2_w, n2_b, nxt);
        float* t = cur; cur = nxt; nxt = t;
    }

    // --- final edge network -> out ---
    edge_kernel<<<edge_blocks, BLK, 0, stream>>>(
        row, col, cur, e1_w, e1_b, e2_w, e2_b, out);
}